// Round 11
// baseline (211.862 us; speedup 1.0000x reference)
//
#include <hip/hip_runtime.h>

#define L 256
#define BATCH 512
#define CIN 32
#define HIDN 128
#define OUTN 512

typedef _Float16 f16x8 __attribute__((ext_vector_type(8)));
typedef float f32x4 __attribute__((ext_vector_type(4)));

#define MFMA16(a, b, c) __builtin_amdgcn_mfma_f32_16x16x32_f16(a, b, c, 0, 0, 0)

static __device__ __forceinline__ unsigned short f16b(_Float16 h) {
    unsigned short u; __builtin_memcpy(&u, &h, 2); return u;
}

// ws layout (bytes):
//   hs      @ 0        (33554432)  fp16 hs[b*32768 + t*128 + j]
//   pooledH @ 33554432 (131072)    fp16 hi of pooled[b*128 + j]
//   pooledL @ 33685504 (131072)    fp16 lo residual
//
// R20: residual closed out (R16-R19: invariant to pool layout/occupancy, gemm
// algorithm, kernel count, XCD affinity -> harness-fixed + ~15-20us real).
// This round attacks rnn's step critical path: the two x-MFMAs don't depend
// on the barrier (operands: prefetched xB + bias), so they're PRE-COMPUTED at
// the end of the previous step (MFMA pipe idle during the VALU epilogue).
// Post-barrier chains start directly at Ah0*Bh0: 3-deep -> 2-deep, and the
// x-read wait leaves the critical window. FLOP order bit-identical
// (Axh*xB+bp still first in the chain).

// MFMA RNN, fp16 2-term split. 32 blocks (16 batch rows) x 512 thr (8 waves,
// 2/SIMD). R16 structure: 4-chain MFMA STEP, prep fused in prologue,
// ^tq staging swizzle; R20: pre-barrier x-MFMA, single x register,
// plain lgkmcnt(0) barrier guard.
__global__ __launch_bounds__(512, 1) void rnn_kernel(
    const float* __restrict__ x, const float* __restrict__ h0,
    const float* __restrict__ W_in, const float* __restrict__ b_in,
    const float* __restrict__ W_ih, const float* __restrict__ b_ih,
    const float* __restrict__ W_hh, const float* __restrict__ b_hh,
    unsigned short* __restrict__ hs)
{
    const int tid = threadIdx.x;
    const int bb = blockIdx.x;
    const int lane = tid & 63;
    const int w = tid >> 6;       // wave 0..7
    const int n = lane & 15;      // batch col / B col
    const int q = lane >> 4;      // quad

    __shared__ unsigned short hbuf[2][16][HIDN];     // 8 KB, granule swizzle ^(n&7)
    __shared__ unsigned short xcl[2][16][64][8];     // 32 KB, [buf][tt][granule][c&7]
    __shared__ float wih_s[128][65];                 // 33.3 KB, +1 pad: banks j+m
    __shared__ float win_s[64][32];                  // 8 KB
    __shared__ float bin_s[64];

    // ---- x chunk staging over 512 threads: i=tid+r*512 -> (nn,cc,tq) ----
    float4 xr[4];
    auto issue_chunk = [&](int ci) {
#pragma unroll
        for (int r = 0; r < 4; ++r) {
            int i = tid + r * 512;
            int nn = i >> 7, cc = (i >> 2) & 31, tq = i & 3;
            xr[r] = *(const float4*)(x + (((size_t)bb * 16 + nn) * CIN + cc) * L + ci * 16 + tq * 4);
        }
    };
    auto write_chunk = [&](int buf) {
#pragma unroll
        for (int r = 0; r < 4; ++r) {
            int i = tid + r * 512;
            int nn = i >> 7, cc = (i >> 2) & 31, tq = i & 3;
            int gr = ((cc >> 3) * 16 + (nn ^ ((cc >> 3) << 2))) ^ tq;  // ^tq: bank-spread
            float vv[4] = {xr[r].x, xr[r].y, xr[r].z, xr[r].w};
#pragma unroll
            for (int k = 0; k < 4; ++k)
                xcl[buf][tq * 4 + k][gr][cc & 7] = f16b((_Float16)vv[k]);
        }
    };

    issue_chunk(0);                       // x loads in flight over the prologue

    // ---- stage small weights to LDS ----
    for (int i = tid; i < 128 * 64; i += 512) wih_s[i >> 6][i & 63] = W_ih[i];
    for (int i = tid; i < 64 * 32; i += 512) ((float*)win_s)[i] = W_in[i];
    if (tid < 64) bin_s[tid] = b_in[tid];

    // ---- h0 -> fp16 plane, dbuf 0 (first 256 threads) ----
    if (tid < 256) {
        const int ni = tid >> 4, gi = tid & 15;
        const float4* src = (const float4*)(h0 + ((size_t)bb * 16 + ni) * HIDN + gi * 8);
        float4 a = src[0], b4 = src[1];
        float vv[8] = {a.x, a.y, a.z, a.w, b4.x, b4.y, b4.z, b4.w};
        unsigned short o[8];
#pragma unroll
        for (int i = 0; i < 8; ++i) o[i] = f16b((_Float16)vv[i]);
        *(uint4*)&hbuf[0][ni][(gi ^ (ni & 7)) * 8] = *(uint4*)o;
    }
    __syncthreads();

    // ---- prologue weight derivation (same FLOP order as old prep_kernel;
    //      verified bit-identical in R15/R16) ----
    const int jr = w * 16 + n;
    f16x8 Ah[4], Al[4];
    const float* wrow = W_hh + jr * HIDN;
#pragma unroll
    for (int kc = 0; kc < 4; ++kc) {
        float4 v0 = *(const float4*)(wrow + kc * 32 + q * 8);
        float4 v1 = *(const float4*)(wrow + kc * 32 + q * 8 + 4);
        float vv[8] = {v0.x, v0.y, v0.z, v0.w, v1.x, v1.y, v1.z, v1.w};
        f16x8 H, Lo;
#pragma unroll
        for (int i = 0; i < 8; ++i) {
            _Float16 hi = (_Float16)vv[i];
            H[i] = hi;
            Lo[i] = (_Float16)(vv[i] - (float)hi);
        }
        Ah[kc] = H; Al[kc] = Lo;
    }
    float acc8[8];
#pragma unroll
    for (int i = 0; i < 8; ++i) acc8[i] = 0.f;
    for (int m = 0; m < 64; ++m) {
        float wv = wih_s[jr][m];                 // pad-65 rows: conflict-free
        const float* wc = &win_s[m][q * 8];
#pragma unroll
        for (int i = 0; i < 8; ++i) acc8[i] += wv * wc[i];
    }
    f16x8 Axh, Axl;
#pragma unroll
    for (int i = 0; i < 8; ++i) {
        _Float16 hi = (_Float16)acc8[i];
        Axh[i] = hi;
        Axl[i] = (_Float16)(acc8[i] - (float)hi);
    }
    const int jb0 = w * 16 + q * 4;
    float bs4[4];
#pragma unroll
    for (int r = 0; r < 4; ++r) bs4[r] = b_ih[jb0 + r] + b_hh[jb0 + r];
    for (int m = 0; m < 64; ++m) {
        float bm = bin_s[m];
#pragma unroll
        for (int r = 0; r < 4; ++r) bs4[r] += wih_s[jb0 + r][m] * bm;
    }
    f32x4 bp = (f32x4){bs4[0], bs4[1], bs4[2], bs4[3]};
    const f32x4 zero4 = (f32x4){0.f, 0.f, 0.f, 0.f};

    // ---- finish x staging ----
    write_chunk(0);
    issue_chunk(1);
    __syncthreads();

    // hs [b][t][j]: pool reads each b-row as one sequential 64-KB stream.
    unsigned short* hsp = hs + ((size_t)bb * 16 + n) * (L * HIDN) + w * 16 + q * 4;
    const int G = (w * 2 + (q >> 1)) ^ (n & 7);
    const int sw = n & 7;
    const int grs = q * 16 + (n ^ (q << 2));   // this lane's xc granule (pre-swz)

    // t=0 x fragment + pre-computed x-MFMAs (bit-identical chain head:
    // pC0 = Axh*xB + bp is exactly the old first MFMA of the c0 chain)
    f16x8 xbn = *(const f16x8*)&xcl[0][0][grs][0];
    f32x4 pC0 = MFMA16(Axh, xbn, bp);
    f32x4 pC2 = MFMA16(Axl, xbn, zero4);

#define STEP(T, IN, OUT, OFF)                                                  \
    {                                                                          \
        f16x8 Bh0 = *(const f16x8*)&hbuf[IN][n][((0 + q) ^ sw) * 8];           \
        f16x8 Bh1 = *(const f16x8*)&hbuf[IN][n][((4 + q) ^ sw) * 8];           \
        f16x8 Bh2 = *(const f16x8*)&hbuf[IN][n][((8 + q) ^ sw) * 8];           \
        f16x8 Bh3 = *(const f16x8*)&hbuf[IN][n][((12 + q) ^ sw) * 8];          \
        xbn = *(const f16x8*)&xcl[(((T) + 1) >> 4) & 1][((T) + 1) & 15]        \
                                [grs ^ ((((T) + 1) & 15) >> 2)][0];            \
        f32x4 c0 = pC0, c2 = pC2;          /* x-part done pre-barrier */       \
        c0 = MFMA16(Ah[0], Bh0, c0);                                           \
        c2 = MFMA16(Al[0], Bh0, c2);                                           \
        f32x4 c1 = MFMA16(Ah[1], Bh1, zero4);                                  \
        f32x4 c3 = MFMA16(Al[1], Bh1, zero4);                                  \
        c0 = MFMA16(Ah[2], Bh2, c0);                                           \
        c2 = MFMA16(Al[2], Bh2, c2);                                           \
        c1 = MFMA16(Ah[3], Bh3, c1);                                           \
        c3 = MFMA16(Al[3], Bh3, c3);                                           \
        if (((T) & 15) == 14 && (T) < L - 16) {                                \
            write_chunk((((T) >> 4) & 1) ^ 1);                                 \
            if ((T) < L - 32) issue_chunk(((T) >> 4) + 2);                     \
        }                                                                      \
        f32x4 acc = (c0 + c1) + (c2 + c3);                                     \
        unsigned short o[4];                                                   \
        for (int r = 0; r < 4; ++r) {                                          \
            float e = __expf(2.f * acc[r]);                                    \
            float hv = 1.f - 2.f * __builtin_amdgcn_rcpf(e + 1.f);             \
            o[r] = f16b((_Float16)hv);                                         \
        }                                                                      \
        uint2 pk; __builtin_memcpy(&pk, o, 8);                                 \
        *(uint2*)&hbuf[OUT][n][G * 8 + (q & 1) * 4] = pk;                      \
        *(uint2*)(hsp + (OFF)) = pk;                                           \
        pC0 = MFMA16(Axh, xbn, bp);        /* next step's x-part: MFMA pipe */ \
        pC2 = MFMA16(Axl, xbn, zero4);     /* idle during VALU epilogue */     \
        asm volatile("" ::: "memory");                                         \
        __builtin_amdgcn_s_waitcnt(0xC07F);  /* lgkmcnt(0) */                  \
        __builtin_amdgcn_s_barrier();                                          \
        asm volatile("" ::: "memory");                                         \
    }

    for (int t = 0; t < L; t += 2) {
        STEP(t,     0, 1, 0);
        STEP(t + 1, 1, 0, HIDN);
        hsp += 2 * HIDN;
    }
#undef STEP
}

// Upsample(16->32, align_corners) + hardswish + mean. 1024 blocks, 256 thr.
// R19 XCD-affinity swizzle kept (neutral-to-tiny-positive, bit-identical).
__global__ __launch_bounds__(256) void pool_kernel(
    const unsigned short* __restrict__ hs,
    unsigned short* __restrict__ pooledH, unsigned short* __restrict__ pooledL)
{
    const int i = blockIdx.x;
    const int k = i & 7, s = i >> 3;           // k: target XCD residue
    const int bb = k + 8 * (s & 3);            // producer rnn block (same XCD)
    const int inner = s >> 2;                  // 0..31: 16 b-rows x 2 jh
    const int b = bb * 16 + (inner >> 1), jh = inner & 1;
    const int tid = threadIdx.x;
    __shared__ unsigned short m[L][72];     // [t][j-local], pad 72
    __shared__ float ps[4][64];

    const unsigned short* src = hs + (size_t)b * (L * HIDN) + jh * 64;
#pragma unroll
    for (int it = 0; it < 8; ++it) {
        int ii = tid + it * 256;            // 256 t x 8 j-octets
        int t = ii >> 3, joc = ii & 7;
        *(uint4*)&m[t][joc * 8] = *(const uint4*)(src + t * HIDN + joc * 8);
    }
    __syncthreads();

    const int jo = tid & 63, oq = tid >> 6;
    float acc = 0.f;
    for (int oy = oq * 8; oy < oq * 8 + 8; ++oy) {
        float ysf = oy * (15.f / 31.f);
        int y0 = (int)ysf; float wy = ysf - (float)y0; int y1 = min(y0 + 1, 15);
        float rb[16];
#pragma unroll
        for (int sx = 0; sx < 16; ++sx) {
            float v0 = (float)*(const _Float16*)&m[y0 * 16 + sx][jo];
            float v1 = (float)*(const _Float16*)&m[y1 * 16 + sx][jo];
            rb[sx] = v0 + wy * (v1 - v0);
        }
#pragma unroll
        for (int ox = 0; ox < 32; ++ox) {
            float xsf = ox * (15.f / 31.f);
            int x0 = (int)xsf; float wx = xsf - (float)x0; int x1 = min(x0 + 1, 15);
            float v = rb[x0] + wx * (rb[x1] - rb[x0]);
            float t6 = fminf(fmaxf(v + 3.f, 0.f), 6.f);
            acc += v * t6;
        }
    }
    ps[oq][jo] = acc;
    __syncthreads();
    if (tid < 64) {
        float p = ((ps[0][tid] + ps[1][tid]) + (ps[2][tid] + ps[3][tid])) * (1.f / 6144.f);
        _Float16 H = (_Float16)p;
        _Float16 Lo = (_Float16)(p - (float)H);
        pooledH[b * HIDN + jh * 64 + tid] = f16b(H);
        pooledL[b * HIDN + jh * 64 + tid] = f16b(Lo);
    }
}

// MFMA out-GEMM: out[512b,512o] = pooled @ W_out^T + b_out. (R18, unchanged)
__global__ __launch_bounds__(512, 1) void out_gemm_kernel(
    const unsigned short* __restrict__ pooledH,
    const unsigned short* __restrict__ pooledL,
    const float* __restrict__ W_out, const float* __restrict__ b_out,
    float* __restrict__ out)
{
    const int tid = threadIdx.x;
    const int bg = blockIdx.x >> 2, oqd = blockIdx.x & 3;
    const int lane = tid & 63;
    const int w = tid >> 6;
    const int bsub = w & 1, osub = w >> 1;
    const int n = lane & 15;          // = MFMA A-row m and B-col n
    const int q = lane >> 4;

    const int bBase = bg * 32 + bsub * 16;
    const int oBase = oqd * 128 + osub * 32;

    f16x8 Ah[2][4], Al[2][4];
#pragma unroll
    for (int tile = 0; tile < 2; ++tile) {
        const float* wrow = W_out + (oBase + tile * 16 + n) * HIDN;
#pragma unroll
        for (int kc = 0; kc < 4; ++kc) {
            float4 v0 = *(const float4*)(wrow + kc * 32 + q * 8);
            float4 v1 = *(const float4*)(wrow + kc * 32 + q * 8 + 4);
            float vv[8] = {v0.x, v0.y, v0.z, v0.w, v1.x, v1.y, v1.z, v1.w};
            f16x8 H, Lo;
#pragma unroll
            for (int i = 0; i < 8; ++i) {
                _Float16 hi = (_Float16)vv[i];
                H[i] = hi;
                Lo[i] = (_Float16)(vv[i] - (float)hi);
            }
            Ah[tile][kc] = H; Al[tile][kc] = Lo;
        }
    }
    f16x8 Bh[4], Bl[4];
#pragma unroll
    for (int kc = 0; kc < 4; ++kc) {
        Bh[kc] = *(const f16x8*)(pooledH + (bBase + n) * HIDN + kc * 32 + q * 8);
        Bl[kc] = *(const f16x8*)(pooledL + (bBase + n) * HIDN + kc * 32 + q * 8);
    }
    const f32x4 zero4 = (f32x4){0.f, 0.f, 0.f, 0.f};

#pragma unroll
    for (int tile = 0; tile < 2; ++tile) {
        float4 bv = *(const float4*)(b_out + oBase + tile * 16 + q * 4);
        f32x4 aHH = (f32x4){bv.x, bv.y, bv.z, bv.w};
        f32x4 aHL = zero4, aLH = zero4;
#pragma unroll
        for (int kc = 0; kc < 4; ++kc) {
            aHH = MFMA16(Ah[tile][kc], Bh[kc], aHH);
            aHL = MFMA16(Ah[tile][kc], Bl[kc], aHL);
            aLH = MFMA16(Al[tile][kc], Bh[kc], aLH);
        }
        f32x4 acc = aHH + (aHL + aLH);
        *(float4*)(out + (size_t)(bBase + n) * OUTN + oBase + tile * 16 + q * 4) =
            *(float4*)&acc;
    }
}

extern "C" void kernel_launch(void* const* d_in, const int* in_sizes, int n_in,
                              void* d_out, int out_size, void* d_ws, size_t ws_size,
                              hipStream_t stream)
{
    const float* x     = (const float*)d_in[0];
    const float* h0    = (const float*)d_in[1];
    const float* W_in  = (const float*)d_in[2];
    const float* b_in  = (const float*)d_in[3];
    const float* W_ih  = (const float*)d_in[4];
    const float* b_ih  = (const float*)d_in[5];
    const float* W_hh  = (const float*)d_in[6];
    const float* b_hh  = (const float*)d_in[7];
    const float* W_out = (const float*)d_in[8];
    const float* b_out = (const float*)d_in[9];
    float* out = (float*)d_out;

    char* wsb = (char*)d_ws;
    unsigned short* hsb     = (unsigned short*)wsb;
    unsigned short* pooledH = (unsigned short*)(wsb + 33554432);
    unsigned short* pooledL = (unsigned short*)(wsb + 33685504);

    rnn_kernel<<<32, 512, 0, stream>>>(x, h0, W_in, b_in, W_ih, b_ih,
                                       W_hh, b_hh, hsb);
    pool_kernel<<<1024, 256, 0, stream>>>(hsb, pooledH, pooledL);
    out_gemm_kernel<<<64, 512, 0, stream>>>(pooledH, pooledL, W_out, b_out, out);
}

// Round 12
// 207.758 us; speedup vs baseline: 1.0198x; 1.0198x over previous
//
#include <hip/hip_runtime.h>

#define L 256
#define BATCH 512
#define CIN 32
#define HIDN 128
#define OUTN 512

typedef _Float16 f16x8 __attribute__((ext_vector_type(8)));
typedef float f32x4 __attribute__((ext_vector_type(4)));

#define MFMA16(a, b, c) __builtin_amdgcn_mfma_f32_16x16x32_f16(a, b, c, 0, 0, 0)

static __device__ __forceinline__ unsigned short f16b(_Float16 h) {
    unsigned short u; __builtin_memcpy(&u, &h, 2); return u;
}

// ws layout (bytes):
//   hs      @ 0        (33554432)  fp16 hs[b*32768 + t*128 + j]
//   pooledH @ 33554432 (131072)    fp16 hi of pooled[b*128 + j]
//   pooledL @ 33685504 (131072)    fp16 lo residual
//
// R21 = exact revert to R19 (best verified, 207.4us). R20's pre-barrier
// x-MFMA regressed (the x-MFMA head was never on the critical path; the step
// is LDS-burst + barrier bound). Final configuration:
//  - rnn: R16 structure (4-chain MFMA STEP, prep fused in prologue, ^tq
//    staging swizzle, lgkmcnt(1) barrier guard w/ xB register prefetch).
//  - pool: R17 split (1024 blocks) + R19 XCD-affinity swizzle.
//  - gemm: R18 MFMA with W_out read once, hi/lo 3-term product.

// MFMA RNN, fp16 2-term split. 32 blocks (16 batch rows) x 512 thr (8 waves,
// 2/SIMD).
__global__ __launch_bounds__(512, 1) void rnn_kernel(
    const float* __restrict__ x, const float* __restrict__ h0,
    const float* __restrict__ W_in, const float* __restrict__ b_in,
    const float* __restrict__ W_ih, const float* __restrict__ b_ih,
    const float* __restrict__ W_hh, const float* __restrict__ b_hh,
    unsigned short* __restrict__ hs)
{
    const int tid = threadIdx.x;
    const int bb = blockIdx.x;
    const int lane = tid & 63;
    const int w = tid >> 6;       // wave 0..7
    const int n = lane & 15;      // batch col / B col
    const int q = lane >> 4;      // quad

    __shared__ unsigned short hbuf[2][16][HIDN];     // 8 KB, granule swizzle ^(n&7)
    __shared__ unsigned short xcl[2][16][64][8];     // 32 KB, [buf][tt][granule][c&7]
    __shared__ float wih_s[128][65];                 // 33.3 KB, +1 pad: banks j+m
    __shared__ float win_s[64][32];                  // 8 KB
    __shared__ float bin_s[64];

    // ---- x chunk staging over 512 threads: i=tid+r*512 -> (nn,cc,tq) ----
    float4 xr[4];
    auto issue_chunk = [&](int ci) {
#pragma unroll
        for (int r = 0; r < 4; ++r) {
            int i = tid + r * 512;
            int nn = i >> 7, cc = (i >> 2) & 31, tq = i & 3;
            xr[r] = *(const float4*)(x + (((size_t)bb * 16 + nn) * CIN + cc) * L + ci * 16 + tq * 4);
        }
    };
    auto write_chunk = [&](int buf) {
#pragma unroll
        for (int r = 0; r < 4; ++r) {
            int i = tid + r * 512;
            int nn = i >> 7, cc = (i >> 2) & 31, tq = i & 3;
            int gr = ((cc >> 3) * 16 + (nn ^ ((cc >> 3) << 2))) ^ tq;  // ^tq: bank-spread
            float vv[4] = {xr[r].x, xr[r].y, xr[r].z, xr[r].w};
#pragma unroll
            for (int k = 0; k < 4; ++k)
                xcl[buf][tq * 4 + k][gr][cc & 7] = f16b((_Float16)vv[k]);
        }
    };

    issue_chunk(0);                       // x loads in flight over the prologue

    // ---- stage small weights to LDS ----
    for (int i = tid; i < 128 * 64; i += 512) wih_s[i >> 6][i & 63] = W_ih[i];
    for (int i = tid; i < 64 * 32; i += 512) ((float*)win_s)[i] = W_in[i];
    if (tid < 64) bin_s[tid] = b_in[tid];

    // ---- h0 -> fp16 plane, dbuf 0 (first 256 threads) ----
    if (tid < 256) {
        const int ni = tid >> 4, gi = tid & 15;
        const float4* src = (const float4*)(h0 + ((size_t)bb * 16 + ni) * HIDN + gi * 8);
        float4 a = src[0], b4 = src[1];
        float vv[8] = {a.x, a.y, a.z, a.w, b4.x, b4.y, b4.z, b4.w};
        unsigned short o[8];
#pragma unroll
        for (int i = 0; i < 8; ++i) o[i] = f16b((_Float16)vv[i]);
        *(uint4*)&hbuf[0][ni][(gi ^ (ni & 7)) * 8] = *(uint4*)o;
    }
    __syncthreads();

    // ---- prologue weight derivation (same FLOP order as old prep_kernel;
    //      verified bit-identical in R15/R16) ----
    const int jr = w * 16 + n;
    f16x8 Ah[4], Al[4];
    const float* wrow = W_hh + jr * HIDN;
#pragma unroll
    for (int kc = 0; kc < 4; ++kc) {
        float4 v0 = *(const float4*)(wrow + kc * 32 + q * 8);
        float4 v1 = *(const float4*)(wrow + kc * 32 + q * 8 + 4);
        float vv[8] = {v0.x, v0.y, v0.z, v0.w, v1.x, v1.y, v1.z, v1.w};
        f16x8 H, Lo;
#pragma unroll
        for (int i = 0; i < 8; ++i) {
            _Float16 hi = (_Float16)vv[i];
            H[i] = hi;
            Lo[i] = (_Float16)(vv[i] - (float)hi);
        }
        Ah[kc] = H; Al[kc] = Lo;
    }
    float acc8[8];
#pragma unroll
    for (int i = 0; i < 8; ++i) acc8[i] = 0.f;
    for (int m = 0; m < 64; ++m) {
        float wv = wih_s[jr][m];                 // pad-65 rows: conflict-free
        const float* wc = &win_s[m][q * 8];
#pragma unroll
        for (int i = 0; i < 8; ++i) acc8[i] += wv * wc[i];
    }
    f16x8 Axh, Axl;
#pragma unroll
    for (int i = 0; i < 8; ++i) {
        _Float16 hi = (_Float16)acc8[i];
        Axh[i] = hi;
        Axl[i] = (_Float16)(acc8[i] - (float)hi);
    }
    const int jb0 = w * 16 + q * 4;
    float bs4[4];
#pragma unroll
    for (int r = 0; r < 4; ++r) bs4[r] = b_ih[jb0 + r] + b_hh[jb0 + r];
    for (int m = 0; m < 64; ++m) {
        float bm = bin_s[m];
#pragma unroll
        for (int r = 0; r < 4; ++r) bs4[r] += wih_s[jb0 + r][m] * bm;
    }
    f32x4 bp = (f32x4){bs4[0], bs4[1], bs4[2], bs4[3]};
    const f32x4 zero4 = (f32x4){0.f, 0.f, 0.f, 0.f};

    // ---- finish x staging ----
    write_chunk(0);
    issue_chunk(1);
    __syncthreads();

    // hs [b][t][j]: pool reads each b-row as one sequential 64-KB stream.
    unsigned short* hsp = hs + ((size_t)bb * 16 + n) * (L * HIDN) + w * 16 + q * 4;
    const int G = (w * 2 + (q >> 1)) ^ (n & 7);
    const int sw = n & 7;
    const int grs = q * 16 + (n ^ (q << 2));   // this lane's xc granule (pre-swz)

    f16x8 xb0, xb1;
    xb0 = *(const f16x8*)&xcl[0][0][grs][0];   // t=0: tt>>2 = 0

#define STEP(T, IN, OUT, OFF, XCUR, XNEXT)                                     \
    {                                                                          \
        f16x8 Bh0 = *(const f16x8*)&hbuf[IN][n][((0 + q) ^ sw) * 8];           \
        f16x8 Bh1 = *(const f16x8*)&hbuf[IN][n][((4 + q) ^ sw) * 8];           \
        f16x8 Bh2 = *(const f16x8*)&hbuf[IN][n][((8 + q) ^ sw) * 8];           \
        f16x8 Bh3 = *(const f16x8*)&hbuf[IN][n][((12 + q) ^ sw) * 8];          \
        f32x4 c0 = MFMA16(Axh, XCUR, bp);      /* operands all in regs */      \
        f32x4 c2 = MFMA16(Axl, XCUR, zero4);                                   \
        c0 = MFMA16(Ah[0], Bh0, c0);                                           \
        c2 = MFMA16(Al[0], Bh0, c2);                                           \
        f32x4 c1 = MFMA16(Ah[1], Bh1, zero4);                                  \
        f32x4 c3 = MFMA16(Al[1], Bh1, zero4);                                  \
        c0 = MFMA16(Ah[2], Bh2, c0);                                           \
        c2 = MFMA16(Al[2], Bh2, c2);                                           \
        c1 = MFMA16(Ah[3], Bh3, c1);                                           \
        c3 = MFMA16(Al[3], Bh3, c3);                                           \
        if (((T) & 15) == 14 && (T) < L - 16) {                                \
            write_chunk((((T) >> 4) & 1) ^ 1);                                 \
            if ((T) < L - 32) issue_chunk(((T) >> 4) + 2);                     \
        }                                                                      \
        f32x4 acc = (c0 + c1) + (c2 + c3);                                     \
        unsigned short o[4];                                                   \
        for (int r = 0; r < 4; ++r) {                                          \
            float e = __expf(2.f * acc[r]);                                    \
            float hv = 1.f - 2.f * __builtin_amdgcn_rcpf(e + 1.f);             \
            o[r] = f16b((_Float16)hv);                                         \
        }                                                                      \
        uint2 pk; __builtin_memcpy(&pk, o, 8);                                 \
        *(uint2*)&hbuf[OUT][n][G * 8 + (q & 1) * 4] = pk;                      \
        *(uint2*)(hsp + (OFF)) = pk;                                           \
        XNEXT = *(const f16x8*)&xcl[(((T) + 1) >> 4) & 1][((T) + 1) & 15]      \
                                  [grs ^ ((((T) + 1) & 15) >> 2)][0];          \
        asm volatile("" ::: "memory");                                         \
        __builtin_amdgcn_s_waitcnt(0xC17F);  /* lgkmcnt(1): writes drained, */ \
        __builtin_amdgcn_s_barrier();        /* xB prefetch stays in flight */ \
        asm volatile("" ::: "memory");                                         \
    }

    for (int t = 0; t < L; t += 2) {
        STEP(t,     0, 1, 0,     xb0, xb1);
        STEP(t + 1, 1, 0, HIDN,  xb1, xb0);
        hsp += 2 * HIDN;
    }
#undef STEP
}

// Upsample(16->32, align_corners) + hardswish + mean. 1024 blocks, 256 thr.
// XCD-affinity block swizzle: block i serves (b, jh) produced by rnn block
// bb ≡ i (mod 8) so (under round-robin dispatch) reads hit the local L2.
__global__ __launch_bounds__(256) void pool_kernel(
    const unsigned short* __restrict__ hs,
    unsigned short* __restrict__ pooledH, unsigned short* __restrict__ pooledL)
{
    const int i = blockIdx.x;
    const int k = i & 7, s = i >> 3;           // k: target XCD residue
    const int bb = k + 8 * (s & 3);            // producer rnn block (same XCD)
    const int inner = s >> 2;                  // 0..31: 16 b-rows x 2 jh
    const int b = bb * 16 + (inner >> 1), jh = inner & 1;
    const int tid = threadIdx.x;
    __shared__ unsigned short m[L][72];     // [t][j-local], pad 72
    __shared__ float ps[4][64];

    const unsigned short* src = hs + (size_t)b * (L * HIDN) + jh * 64;
#pragma unroll
    for (int it = 0; it < 8; ++it) {
        int ii = tid + it * 256;            // 256 t x 8 j-octets
        int t = ii >> 3, joc = ii & 7;
        *(uint4*)&m[t][joc * 8] = *(const uint4*)(src + t * HIDN + joc * 8);
    }
    __syncthreads();

    const int jo = tid & 63, oq = tid >> 6;
    float acc = 0.f;
    for (int oy = oq * 8; oy < oq * 8 + 8; ++oy) {
        float ysf = oy * (15.f / 31.f);
        int y0 = (int)ysf; float wy = ysf - (float)y0; int y1 = min(y0 + 1, 15);
        float rb[16];
#pragma unroll
        for (int sx = 0; sx < 16; ++sx) {
            float v0 = (float)*(const _Float16*)&m[y0 * 16 + sx][jo];
            float v1 = (float)*(const _Float16*)&m[y1 * 16 + sx][jo];
            rb[sx] = v0 + wy * (v1 - v0);
        }
#pragma unroll
        for (int ox = 0; ox < 32; ++ox) {
            float xsf = ox * (15.f / 31.f);
            int x0 = (int)xsf; float wx = xsf - (float)x0; int x1 = min(x0 + 1, 15);
            float v = rb[x0] + wx * (rb[x1] - rb[x0]);
            float t6 = fminf(fmaxf(v + 3.f, 0.f), 6.f);
            acc += v * t6;
        }
    }
    ps[oq][jo] = acc;
    __syncthreads();
    if (tid < 64) {
        float p = ((ps[0][tid] + ps[1][tid]) + (ps[2][tid] + ps[3][tid])) * (1.f / 6144.f);
        _Float16 H = (_Float16)p;
        _Float16 Lo = (_Float16)(p - (float)H);
        pooledH[b * HIDN + jh * 64 + tid] = f16b(H);
        pooledL[b * HIDN + jh * 64 + tid] = f16b(Lo);
    }
}

// MFMA out-GEMM: out[512b,512o] = pooled @ W_out^T + b_out.
__global__ __launch_bounds__(512, 1) void out_gemm_kernel(
    const unsigned short* __restrict__ pooledH,
    const unsigned short* __restrict__ pooledL,
    const float* __restrict__ W_out, const float* __restrict__ b_out,
    float* __restrict__ out)
{
    const int tid = threadIdx.x;
    const int bg = blockIdx.x >> 2, oqd = blockIdx.x & 3;
    const int lane = tid & 63;
    const int w = tid >> 6;
    const int bsub = w & 1, osub = w >> 1;
    const int n = lane & 15;          // = MFMA A-row m and B-col n
    const int q = lane >> 4;

    const int bBase = bg * 32 + bsub * 16;
    const int oBase = oqd * 128 + osub * 32;

    f16x8 Ah[2][4], Al[2][4];
#pragma unroll
    for (int tile = 0; tile < 2; ++tile) {
        const float* wrow = W_out + (oBase + tile * 16 + n) * HIDN;
#pragma unroll
        for (int kc = 0; kc < 4; ++kc) {
            float4 v0 = *(const float4*)(wrow + kc * 32 + q * 8);
            float4 v1 = *(const float4*)(wrow + kc * 32 + q * 8 + 4);
            float vv[8] = {v0.x, v0.y, v0.z, v0.w, v1.x, v1.y, v1.z, v1.w};
            f16x8 H, Lo;
#pragma unroll
            for (int i = 0; i < 8; ++i) {
                _Float16 hi = (_Float16)vv[i];
                H[i] = hi;
                Lo[i] = (_Float16)(vv[i] - (float)hi);
            }
            Ah[tile][kc] = H; Al[tile][kc] = Lo;
        }
    }
    f16x8 Bh[4], Bl[4];
#pragma unroll
    for (int kc = 0; kc < 4; ++kc) {
        Bh[kc] = *(const f16x8*)(pooledH + (bBase + n) * HIDN + kc * 32 + q * 8);
        Bl[kc] = *(const f16x8*)(pooledL + (bBase + n) * HIDN + kc * 32 + q * 8);
    }
    const f32x4 zero4 = (f32x4){0.f, 0.f, 0.f, 0.f};

#pragma unroll
    for (int tile = 0; tile < 2; ++tile) {
        float4 bv = *(const float4*)(b_out + oBase + tile * 16 + q * 4);
        f32x4 aHH = (f32x4){bv.x, bv.y, bv.z, bv.w};
        f32x4 aHL = zero4, aLH = zero4;
#pragma unroll
        for (int kc = 0; kc < 4; ++kc) {
            aHH = MFMA16(Ah[tile][kc], Bh[kc], aHH);
            aHL = MFMA16(Ah[tile][kc], Bl[kc], aHL);
            aLH = MFMA16(Al[tile][kc], Bh[kc], aLH);
        }
        f32x4 acc = aHH + (aHL + aLH);
        *(float4*)(out + (size_t)(bBase + n) * OUTN + oBase + tile * 16 + q * 4) =
            *(float4*)&acc;
    }
}

extern "C" void kernel_launch(void* const* d_in, const int* in_sizes, int n_in,
                              void* d_out, int out_size, void* d_ws, size_t ws_size,
                              hipStream_t stream)
{
    const float* x     = (const float*)d_in[0];
    const float* h0    = (const float*)d_in[1];
    const float* W_in  = (const float*)d_in[2];
    const float* b_in  = (const float*)d_in[3];
    const float* W_ih  = (const float*)d_in[4];
    const float* b_ih  = (const float*)d_in[5];
    const float* W_hh  = (const float*)d_in[6];
    const float* b_hh  = (const float*)d_in[7];
    const float* W_out = (const float*)d_in[8];
    const float* b_out = (const float*)d_in[9];
    float* out = (float*)d_out;

    char* wsb = (char*)d_ws;
    unsigned short* hsb     = (unsigned short*)wsb;
    unsigned short* pooledH = (unsigned short*)(wsb + 33554432);
    unsigned short* pooledL = (unsigned short*)(wsb + 33685504);

    rnn_kernel<<<32, 512, 0, stream>>>(x, h0, W_in, b_in, W_ih, b_ih,
                                       W_hh, b_hh, hsb);
    pool_kernel<<<1024, 256, 0, stream>>>(hsb, pooledH, pooledL);
    out_gemm_kernel<<<64, 512, 0, stream>>>(pooledH, pooledL, W_out, b_out, out);
}